// Round 2
// baseline (34850.299 us; speedup 1.0000x reference)
//
#include <hip/hip_runtime.h>
#include <cstdint>
#include <cstddef>

// Problem constants
constexpr int kB = 64;
constexpr int kT = 512;
constexpr int kD = 128;
constexpr int kH = 512;
constexpr int kLat = 128;

// Workspace layout (float element offsets) — total ~85.1 MB
constexpr size_t HB       = (size_t)kH * kB;            // 32,768
constexpr size_t OFF_XT   = 0;                          // XT[t][d][b], 512*128*64
constexpr size_t XT_ELEMS = (size_t)kT * kD * kB;       // 4,194,304
constexpr size_t OFF_Y    = OFF_XT + XT_ELEMS;          // y[t][j][b], 511*512*64
constexpr size_t Y_ELEMS  = (size_t)(kT - 1) * kH * kB; // 16,744,448
constexpr size_t OFF_HTF  = OFF_Y + Y_ELEMS;            // h double-buffer fwd [2][H][B]
constexpr size_t OFF_HTB  = OFF_HTF + 2 * HB;           // h double-buffer bwd
constexpr size_t OFF_HTD  = OFF_HTB + 2 * HB;           // h double-buffer dec
constexpr size_t OFF_HFF  = OFF_HTD + 2 * HB;           // final h fwd [H][B]
constexpr size_t OFF_HFB  = OFF_HFF + HB;               // final h bwd
constexpr size_t OFF_HSF  = OFF_HFB + HB;               // masked h-sum fwd
constexpr size_t OFF_HSB  = OFF_HSF + HB;               // masked h-sum bwd
constexpr size_t OFF_BAR  = OFF_HSB + HB;               // barrier ints (256 ints)
constexpr size_t NEED_BYTES = (OFF_BAR + 256) * sizeof(float); // 85,066,752

__device__ __forceinline__ float sigf(float x) { return 1.0f / (1.0f + __expf(-x)); }

// Sense-reversing barrier over nwg workgroups (device-scope atomics).
__device__ __forceinline__ void grid_barrier(int* cnt, int* gen, int nwg) {
  __syncthreads();
  if (threadIdx.x == 0) {
    __threadfence();
    int g = __hip_atomic_load(gen, __ATOMIC_RELAXED, __HIP_MEMORY_SCOPE_AGENT);
    int t = __hip_atomic_fetch_add(cnt, 1, __ATOMIC_ACQ_REL, __HIP_MEMORY_SCOPE_AGENT);
    if (t == nwg - 1) {
      __hip_atomic_store(cnt, 0, __ATOMIC_RELAXED, __HIP_MEMORY_SCOPE_AGENT);
      __hip_atomic_fetch_add(gen, 1, __ATOMIC_ACQ_REL, __HIP_MEMORY_SCOPE_AGENT);
    } else {
      while (__hip_atomic_load(gen, __ATOMIC_ACQUIRE, __HIP_MEMORY_SCOPE_AGENT) == g) {
        __builtin_amdgcn_s_sleep(2);
      }
    }
    __threadfence();
  }
  __syncthreads();
}

// One-time transpose: XT[t][d][b] = X[b][t][d]. One block per t.
__global__ __launch_bounds__(256) void xt_k(const float* __restrict__ X,
                                            float* __restrict__ ws) {
  __shared__ float L[128 * 65];
  const int t = blockIdx.x;
  const int tid = threadIdx.x;
  #pragma unroll
  for (int i = 0; i < 8; ++i) {
    const int l = tid + i * 256;        // float4 load index
    const int b = l >> 5, dq = l & 31;  // 32 float4 per b-row
    const float4 v = *(const float4*)(X + ((size_t)b * kT + t) * kD + dq * 4);
    L[(dq * 4 + 0) * 65 + b] = v.x;
    L[(dq * 4 + 1) * 65 + b] = v.y;
    L[(dq * 4 + 2) * 65 + b] = v.z;
    L[(dq * 4 + 3) * 65 + b] = v.w;
  }
  __syncthreads();
  float* dst = ws + OFF_XT + (size_t)t * (kD * kB);
  #pragma unroll
  for (int i = 0; i < 8; ++i) {
    const int w = tid + i * 256;        // float4 store index; w*4 = d*64 + b0
    const int d = w >> 4, b0 = (w & 15) * 4;
    float4 o;
    o.x = L[d * 65 + b0 + 0];
    o.y = L[d * 65 + b0 + 1];
    o.z = L[d * 65 + b0 + 2];
    o.w = L[d * 65 + b0 + 3];
    *(float4*)(dst + w * 4) = o;
  }
}

// Persistent encoder with fused input projection.
// WGs 0..127 forward LSTM, 128..255 backward LSTM (independent barriers).
// WG owns 4 hidden units x 64 batch; thread (s,b) owns hidden j0+s, batch b, 4 gates.
__global__ __launch_bounds__(256) void lstm_enc(
    const float* __restrict__ Whh_f, const float* __restrict__ Whh_b,
    const float* __restrict__ Wih_f, const float* __restrict__ Wih_b,
    const float* __restrict__ bf,    const float* __restrict__ bb,
    const int* __restrict__ lengths, float* __restrict__ ws)
{
  __shared__ __align__(16) float Wl[16 * 512];     // recurrent rows, 32KB, staged once
  __shared__ __align__(16) float Wi[16 * 128];     // input rows, 8KB, staged once
  __shared__ __align__(16) float Xs[128 * 64];     // X_t tile [d][b], 32KB
  __shared__ __align__(16) float hbuf[128 * 64];   // h chunk [k][b], 32KB
  const int wg  = blockIdx.x;
  const bool fwd = wg < 128;
  const int wid = fwd ? wg : wg - 128;
  const int j0  = wid * 4;
  const float* Whh  = fwd ? Whh_f : Whh_b;
  const float* Wih  = fwd ? Wih_f : Wih_b;
  const float* bias = fwd ? bf : bb;
  float* hT   = ws + (fwd ? OFF_HTF : OFF_HTB);
  float* hfin = ws + (fwd ? OFF_HFF : OFF_HFB);
  float* hsum = ws + (fwd ? OFF_HSF : OFF_HSB);
  int* bar = (int*)(ws + OFF_BAR) + (fwd ? 0 : 64);  // cnt at +0, gen at +32 ints
  const int tid = threadIdx.x;

  for (int e = tid; e < 16 * 512; e += 256) {
    const int row = e >> 9, k = e & 511;
    const int gate = row >> 2, ss = row & 3;
    Wl[e] = Whh[((size_t)(gate * kH + j0 + ss)) * kH + k];
  }
  for (int e = tid; e < 16 * 128; e += 256) {
    const int row = e >> 7, d = e & 127;
    const int gate = row >> 2, ss = row & 3;
    Wi[e] = Wih[((size_t)(gate * kH + j0 + ss)) * kD + d];
  }
  hT[wid * 256 + tid] = 0.0f;  // zero h buffer 0 across the 128 WGs of this direction

  const int s = tid >> 6, b = tid & 63;
  const int j = j0 + s;
  const int len_b = lengths[b];
  const float bias0 = bias[0 * kH + j];
  const float bias1 = bias[1 * kH + j];
  const float bias2 = bias[2 * kH + j];
  const float bias3 = bias[3 * kH + j];
  float c = 0.f, hsum_r = 0.f, hval = 0.f;
  grid_barrier(bar, bar + 32, 128);   // also covers LDS weight staging + h zeroing
  int cur = 0;
  for (int t = 0; t < kT; ++t) {
    const int tx = fwd ? t : (kT - 1 - t);
    // stage X_t tile (linear copy; XT already [d][b])
    {
      const float4* s4 = (const float4*)(ws + OFF_XT + (size_t)tx * (kD * kB));
      float4* d4 = (float4*)Xs;
      #pragma unroll
      for (int i = 0; i < 8; ++i) d4[tid + i * 256] = s4[tid + i * 256];
    }
    __syncthreads();
    float acc0 = bias0, acc1 = bias1, acc2 = bias2, acc3 = bias3;
    // fused input projection: 128 k
    {
      const float4* Ip0 = (const float4*)&Wi[(0 * 4 + s) * 128];
      const float4* Ip1 = (const float4*)&Wi[(1 * 4 + s) * 128];
      const float4* Ip2 = (const float4*)&Wi[(2 * 4 + s) * 128];
      const float4* Ip3 = (const float4*)&Wi[(3 * 4 + s) * 128];
      #pragma unroll 4
      for (int k4 = 0; k4 < 32; ++k4) {
        const float4 w0 = Ip0[k4];
        const float4 w1 = Ip1[k4];
        const float4 w2 = Ip2[k4];
        const float4 w3 = Ip3[k4];
        const float x0 = Xs[(k4 * 4 + 0) * 64 + b];
        const float x1 = Xs[(k4 * 4 + 1) * 64 + b];
        const float x2 = Xs[(k4 * 4 + 2) * 64 + b];
        const float x3 = Xs[(k4 * 4 + 3) * 64 + b];
        acc0 += w0.x * x0 + w0.y * x1 + w0.z * x2 + w0.w * x3;
        acc1 += w1.x * x0 + w1.y * x1 + w1.z * x2 + w1.w * x3;
        acc2 += w2.x * x0 + w2.y * x1 + w2.z * x2 + w2.w * x3;
        acc3 += w3.x * x0 + w3.y * x1 + w3.z * x2 + w3.w * x3;
      }
    }
    // recurrent part: 4 chunks of 128 k
    const float* hc = hT + cur * (int)HB;
    for (int ch = 0; ch < 4; ++ch) {
      __syncthreads();
      {
        const float4* s4 = (const float4*)(hc + ch * 128 * 64);
        float4* d4 = (float4*)hbuf;
        #pragma unroll
        for (int i = 0; i < 8; ++i) d4[tid + i * 256] = s4[tid + i * 256];
      }
      __syncthreads();
      const int kb = ch * 128;
      const float4* Wp0 = (const float4*)&Wl[(0 * 4 + s) * 512 + kb];
      const float4* Wp1 = (const float4*)&Wl[(1 * 4 + s) * 512 + kb];
      const float4* Wp2 = (const float4*)&Wl[(2 * 4 + s) * 512 + kb];
      const float4* Wp3 = (const float4*)&Wl[(3 * 4 + s) * 512 + kb];
      #pragma unroll 4
      for (int k4 = 0; k4 < 32; ++k4) {
        const float4 w0 = Wp0[k4];
        const float4 w1 = Wp1[k4];
        const float4 w2 = Wp2[k4];
        const float4 w3 = Wp3[k4];
        const float h0 = hbuf[(k4 * 4 + 0) * 64 + b];
        const float h1 = hbuf[(k4 * 4 + 1) * 64 + b];
        const float h2 = hbuf[(k4 * 4 + 2) * 64 + b];
        const float h3 = hbuf[(k4 * 4 + 3) * 64 + b];
        acc0 += w0.x * h0 + w0.y * h1 + w0.z * h2 + w0.w * h3;
        acc1 += w1.x * h0 + w1.y * h1 + w1.z * h2 + w1.w * h3;
        acc2 += w2.x * h0 + w2.y * h1 + w2.z * h2 + w2.w * h3;
        acc3 += w3.x * h0 + w3.y * h1 + w3.z * h2 + w3.w * h3;
      }
    }
    const float ig = sigf(acc0);
    const float fg = sigf(acc1);
    const float gg = tanhf(acc2);
    const float og = sigf(acc3);
    c = fg * c + ig * gg;
    hval = og * tanhf(c);
    hT[(cur ^ 1) * (int)HB + j * kB + b] = hval;
    const bool m = fwd ? (t < len_b) : (t >= kT - len_b);
    if (m) hsum_r += hval;
    grid_barrier(bar, bar + 32, 128);
    cur ^= 1;
  }
  hfin[j * kB + b] = hval;
  hsum[j * kB + b] = hsum_r;
}

// latent = [hf, hb, mean_f, mean_b] @ W_lat^T + b_lat ; h_dec = latent @ W_l2h^T + b_l2h
// one WG per batch element; writes h_dec into decoder h buffer 0.
__global__ __launch_bounds__(256) void latent_k(
    const float* __restrict__ W_lat, const float* __restrict__ b_lat,
    const float* __restrict__ W_l2h, const float* __restrict__ b_l2h,
    const int* __restrict__ lengths, float* __restrict__ ws)
{
  __shared__ __align__(16) float li[4 * kH];
  __shared__ __align__(16) float ls[kLat];
  const int b = blockIdx.x;
  const int tid = threadIdx.x;
  const float invlen = 1.0f / (float)lengths[b];
  for (int j = tid; j < kH; j += 256) {
    li[j]           = ws[OFF_HFF + (size_t)j * kB + b];
    li[kH + j]      = ws[OFF_HFB + (size_t)j * kB + b];
    li[2 * kH + j]  = ws[OFF_HSF + (size_t)j * kB + b] * invlen;
    li[3 * kH + j]  = ws[OFF_HSB + (size_t)j * kB + b] * invlen;
  }
  __syncthreads();
  if (tid < kLat) {
    const float* w = W_lat + (size_t)tid * (4 * kH);
    float a = b_lat[tid];
    for (int k = 0; k < 4 * kH; k += 4) {
      const float4 wv = *(const float4*)(w + k);
      a += wv.x * li[k] + wv.y * li[k + 1] + wv.z * li[k + 2] + wv.w * li[k + 3];
    }
    ls[tid] = a;
  }
  __syncthreads();
  for (int j = tid; j < kH; j += 256) {
    const float* w = W_l2h + (size_t)j * kLat;
    float a = b_l2h[j];
    #pragma unroll
    for (int k = 0; k < kLat; k += 4) {
      const float4 wv = *(const float4*)(w + k);
      a += wv.x * ls[k] + wv.y * ls[k + 1] + wv.z * ls[k + 2] + wv.w * ls[k + 3];
    }
    ws[OFF_HTD + (size_t)j * kB + b] = a;  // decoder h0 (buffer 0)
  }
}

// Persistent decoder LSTM with fused input projection: 128 WGs, 511 steps,
// writes y[t][j][b] into OFF_Y.
__global__ __launch_bounds__(256) void lstm_dec(
    const float* __restrict__ Whh_d, const float* __restrict__ Wih_d,
    const float* __restrict__ bd, float* __restrict__ ws)
{
  __shared__ __align__(16) float Wl[16 * 512];
  __shared__ __align__(16) float Wi[16 * 128];
  __shared__ __align__(16) float Xs[128 * 64];
  __shared__ __align__(16) float hbuf[128 * 64];
  const int wid = blockIdx.x;
  const int j0 = wid * 4;
  float* hT = ws + OFF_HTD;
  float* y  = ws + OFF_Y;
  int* bar = (int*)(ws + OFF_BAR) + 128;
  const int tid = threadIdx.x;
  for (int e = tid; e < 16 * 512; e += 256) {
    const int row = e >> 9, k = e & 511;
    const int gate = row >> 2, ss = row & 3;
    Wl[e] = Whh_d[((size_t)(gate * kH + j0 + ss)) * kH + k];
  }
  for (int e = tid; e < 16 * 128; e += 256) {
    const int row = e >> 7, d = e & 127;
    const int gate = row >> 2, ss = row & 3;
    Wi[e] = Wih_d[((size_t)(gate * kH + j0 + ss)) * kD + d];
  }
  const int s = tid >> 6, b = tid & 63;
  const int j = j0 + s;
  const float bias0 = bd[0 * kH + j];
  const float bias1 = bd[1 * kH + j];
  const float bias2 = bd[2 * kH + j];
  const float bias3 = bd[3 * kH + j];
  float c = 0.f;
  grid_barrier(bar, bar + 32, 128);   // covers LDS staging; h0 came from latent_k
  int cur = 0;
  for (int t = 0; t < kT - 1; ++t) {
    {
      const float4* s4 = (const float4*)(ws + OFF_XT + (size_t)t * (kD * kB));
      float4* d4 = (float4*)Xs;
      #pragma unroll
      for (int i = 0; i < 8; ++i) d4[tid + i * 256] = s4[tid + i * 256];
    }
    __syncthreads();
    float acc0 = bias0, acc1 = bias1, acc2 = bias2, acc3 = bias3;
    {
      const float4* Ip0 = (const float4*)&Wi[(0 * 4 + s) * 128];
      const float4* Ip1 = (const float4*)&Wi[(1 * 4 + s) * 128];
      const float4* Ip2 = (const float4*)&Wi[(2 * 4 + s) * 128];
      const float4* Ip3 = (const float4*)&Wi[(3 * 4 + s) * 128];
      #pragma unroll 4
      for (int k4 = 0; k4 < 32; ++k4) {
        const float4 w0 = Ip0[k4];
        const float4 w1 = Ip1[k4];
        const float4 w2 = Ip2[k4];
        const float4 w3 = Ip3[k4];
        const float x0 = Xs[(k4 * 4 + 0) * 64 + b];
        const float x1 = Xs[(k4 * 4 + 1) * 64 + b];
        const float x2 = Xs[(k4 * 4 + 2) * 64 + b];
        const float x3 = Xs[(k4 * 4 + 3) * 64 + b];
        acc0 += w0.x * x0 + w0.y * x1 + w0.z * x2 + w0.w * x3;
        acc1 += w1.x * x0 + w1.y * x1 + w1.z * x2 + w1.w * x3;
        acc2 += w2.x * x0 + w2.y * x1 + w2.z * x2 + w2.w * x3;
        acc3 += w3.x * x0 + w3.y * x1 + w3.z * x2 + w3.w * x3;
      }
    }
    const float* hc = hT + cur * (int)HB;
    for (int ch = 0; ch < 4; ++ch) {
      __syncthreads();
      {
        const float4* s4 = (const float4*)(hc + ch * 128 * 64);
        float4* d4 = (float4*)hbuf;
        #pragma unroll
        for (int i = 0; i < 8; ++i) d4[tid + i * 256] = s4[tid + i * 256];
      }
      __syncthreads();
      const int kb = ch * 128;
      const float4* Wp0 = (const float4*)&Wl[(0 * 4 + s) * 512 + kb];
      const float4* Wp1 = (const float4*)&Wl[(1 * 4 + s) * 512 + kb];
      const float4* Wp2 = (const float4*)&Wl[(2 * 4 + s) * 512 + kb];
      const float4* Wp3 = (const float4*)&Wl[(3 * 4 + s) * 512 + kb];
      #pragma unroll 4
      for (int k4 = 0; k4 < 32; ++k4) {
        const float4 w0 = Wp0[k4];
        const float4 w1 = Wp1[k4];
        const float4 w2 = Wp2[k4];
        const float4 w3 = Wp3[k4];
        const float h0 = hbuf[(k4 * 4 + 0) * 64 + b];
        const float h1 = hbuf[(k4 * 4 + 1) * 64 + b];
        const float h2 = hbuf[(k4 * 4 + 2) * 64 + b];
        const float h3 = hbuf[(k4 * 4 + 3) * 64 + b];
        acc0 += w0.x * h0 + w0.y * h1 + w0.z * h2 + w0.w * h3;
        acc1 += w1.x * h0 + w1.y * h1 + w1.z * h2 + w1.w * h3;
        acc2 += w2.x * h0 + w2.y * h1 + w2.z * h2 + w2.w * h3;
        acc3 += w3.x * h0 + w3.y * h1 + w3.z * h2 + w3.w * h3;
      }
    }
    const float ig = sigf(acc0);
    const float fg = sigf(acc1);
    const float gg = tanhf(acc2);
    const float og = sigf(acc3);
    c = fg * c + ig * gg;
    const float hval = og * tanhf(c);
    hT[(cur ^ 1) * (int)HB + j * kB + b] = hval;
    y[((size_t)t * kH + j) * kB + b] = hval;
    grid_barrier(bar, bar + 32, 128);
    cur ^= 1;
  }
}

// decoded = y @ W_out^T + b_out ; out = alpha*decoded + (1-alpha)*X[:,1:,:]
__global__ __launch_bounds__(256) void out_k(
    const float* __restrict__ X, const float* __restrict__ W_out,
    const float* __restrict__ b_out, const float* __restrict__ alpha_p,
    const float* __restrict__ ws, float* __restrict__ out)
{
  __shared__ __align__(16) float ys[128 * 64];    // [k][b]
  __shared__ __align__(16) float Wo[128 * 128];   // [k][d]
  const int t = blockIdx.x;  // 0..510
  const float* y = ws + OFF_Y + (size_t)t * kH * kB;
  const int tid = threadIdx.x;
  float acc[8][4];
  #pragma unroll
  for (int i = 0; i < 8; ++i)
    #pragma unroll
    for (int jj = 0; jj < 4; ++jj) acc[i][jj] = 0.f;
  const int tg = tid >> 4, tb = tid & 15;
  const int d0 = tg * 8, b0 = tb * 4;
  for (int ch = 0; ch < 4; ++ch) {
    __syncthreads();
    {
      const float4* s4 = (const float4*)(y + ch * 128 * 64);
      float4* d4 = (float4*)ys;
      #pragma unroll
      for (int i = 0; i < 8; ++i) d4[tid + i * 256] = s4[tid + i * 256];
    }
    {
      const int d = tid & 127, k0 = (tid >> 7) * 64;
      const float* src = W_out + (size_t)d * kH + ch * 128 + k0;
      #pragma unroll
      for (int i = 0; i < 64; i += 4) {
        float4 v = *(const float4*)(src + i);
        Wo[(k0 + i + 0) * 128 + d] = v.x;
        Wo[(k0 + i + 1) * 128 + d] = v.y;
        Wo[(k0 + i + 2) * 128 + d] = v.z;
        Wo[(k0 + i + 3) * 128 + d] = v.w;
      }
    }
    __syncthreads();
    #pragma unroll 2
    for (int k = 0; k < 128; ++k) {
      const float4 yv = *(const float4*)&ys[k * 64 + b0];
      const float4 w0 = *(const float4*)&Wo[k * 128 + d0];
      const float4 w1 = *(const float4*)&Wo[k * 128 + d0 + 4];
      const float wv[8] = {w0.x, w0.y, w0.z, w0.w, w1.x, w1.y, w1.z, w1.w};
      const float ya[4] = {yv.x, yv.y, yv.z, yv.w};
      #pragma unroll
      for (int di = 0; di < 8; ++di)
        #pragma unroll
        for (int bi = 0; bi < 4; ++bi)
          acc[di][bi] += wv[di] * ya[bi];
    }
  }
  const float alpha = sigf(alpha_p[0]);
  const float beta = 1.0f - alpha;
  #pragma unroll
  for (int bi = 0; bi < 4; ++bi) {
    const int b = b0 + bi;
    const float* xrow = X + ((size_t)b * kT + t + 1) * kD + d0;
    float* orow = out + ((size_t)b * (kT - 1) + t) * kD + d0;
    #pragma unroll
    for (int di = 0; di < 8; di += 4) {
      const float4 xv = *(const float4*)(xrow + di);
      float4 o;
      o.x = alpha * (acc[di + 0][bi] + b_out[d0 + di + 0]) + beta * xv.x;
      o.y = alpha * (acc[di + 1][bi] + b_out[d0 + di + 1]) + beta * xv.y;
      o.z = alpha * (acc[di + 2][bi] + b_out[d0 + di + 2]) + beta * xv.z;
      o.w = alpha * (acc[di + 3][bi] + b_out[d0 + di + 3]) + beta * xv.w;
      *(float4*)(orow + di) = o;
    }
  }
}

// Diagnostic fallback if workspace is too small: out = (1-alpha)*X[:,1:,:]
__global__ __launch_bounds__(256) void fallback_k(
    const float* __restrict__ X, const float* __restrict__ alpha_p,
    float* __restrict__ out, int n)
{
  const int o = blockIdx.x * 256 + threadIdx.x;
  if (o >= n) return;
  const float alpha = sigf(alpha_p[0]);
  const int b = o / ((kT - 1) * kD);
  const int r = o % ((kT - 1) * kD);
  const int t = r / kD, d = r % kD;
  out[o] = (1.0f - alpha) * X[((size_t)b * kT + t + 1) * kD + d];
}

extern "C" void kernel_launch(void* const* d_in, const int* in_sizes, int n_in,
                              void* d_out, int out_size, void* d_ws, size_t ws_size,
                              hipStream_t stream) {
  const float* X      = (const float*)d_in[0];
  const int*   lens   = (const int*)  d_in[1];
  const float* W_ih_f = (const float*)d_in[2];
  const float* W_hh_f = (const float*)d_in[3];
  const float* b_f    = (const float*)d_in[4];
  const float* W_ih_b = (const float*)d_in[5];
  const float* W_hh_b = (const float*)d_in[6];
  const float* b_b    = (const float*)d_in[7];
  const float* W_ih_d = (const float*)d_in[8];
  const float* W_hh_d = (const float*)d_in[9];
  const float* b_d    = (const float*)d_in[10];
  const float* W_lat  = (const float*)d_in[11];
  const float* b_lat  = (const float*)d_in[12];
  const float* W_l2h  = (const float*)d_in[13];
  const float* b_l2h  = (const float*)d_in[14];
  const float* W_out  = (const float*)d_in[15];
  const float* b_out  = (const float*)d_in[16];
  const float* alpha  = (const float*)d_in[17];
  float* ws  = (float*)d_ws;
  float* out = (float*)d_out;

  if (ws_size < NEED_BYTES) {
    // Workspace too small for the real algorithm — produce the recognizable
    // skip-path output instead of faulting (diagnostic).
    fallback_k<<<(out_size + 255) / 256, 256, 0, stream>>>(X, alpha, out, out_size);
    return;
  }

  // zero barrier counters (ws is poisoned 0xAA)
  hipMemsetAsync((void*)(ws + OFF_BAR), 0, 256 * sizeof(int), stream);

  // one-time transpose X -> XT[t][d][b]
  xt_k<<<kT, 256, 0, stream>>>(X, ws);
  // persistent fwd+bwd encoder LSTMs (fused input projection)
  lstm_enc<<<256, 256, 0, stream>>>(W_hh_f, W_hh_b, W_ih_f, W_ih_b, b_f, b_b, lens, ws);
  // latent + decoder initial hidden
  latent_k<<<64, 256, 0, stream>>>(W_lat, b_lat, W_l2h, b_l2h, lens, ws);
  // persistent decoder LSTM (fused input projection; y into OFF_Y)
  lstm_dec<<<128, 256, 0, stream>>>(W_hh_d, W_ih_d, b_d, ws);
  // output projection + skip connection
  out_k<<<kT - 1, 256, 0, stream>>>(X, W_out, b_out, alpha, ws, out);
}

// Round 3
// 10506.857 us; speedup vs baseline: 3.3169x; 3.3169x over previous
//
#include <hip/hip_runtime.h>
#include <cstdint>
#include <cstddef>

typedef __attribute__((ext_vector_type(8))) short bf16x8;
typedef __attribute__((ext_vector_type(4))) float f32x4;
typedef unsigned short ushort_t;

// Problem constants
constexpr int kB = 64;
constexpr int kT = 512;
constexpr int kD = 128;
constexpr int kH = 512;
constexpr int kLat = 128;

// Workspace layout (float element offsets), total ~76.3 MB
constexpr size_t OFF_Y   = 0;                        // fp32 y [511][512][64]
constexpr size_t Y_EL    = (size_t)(kT - 1) * kH * kB;      // 16,744,448
constexpr size_t OFF_XBF = OFF_Y + Y_EL;             // bf16 Xbf [512][64][128] (as ushort)
constexpr size_t XBF_F   = (size_t)kT * kB * kD / 2; // 2,097,152 floats
constexpr size_t OFF_HT  = OFF_XBF + XBF_F;          // bf16 hT: 3 dirs x 2 bufs x 64x512 us
constexpr size_t HT_F    = 3 * 2 * 32768 / 2;        // 98,304 floats
constexpr size_t OFF_RDY = OFF_HT + HT_F;            // 2048 ints (f:0..511, b:512.., d:1024..)
constexpr size_t OFF_HFF = OFF_RDY + 2048;           // fp32 [j][b]
constexpr size_t OFF_HFB = OFF_HFF + 32768;
constexpr size_t OFF_HSF = OFF_HFB + 32768;
constexpr size_t OFF_HSB = OFF_HSF + 32768;
constexpr size_t NEED_BYTES = (OFF_HSB + 32768) * 4; // 76,292,096

#define MFMA_B16(A, Bv, C) C = __builtin_amdgcn_mfma_f32_16x16x32_bf16(A, Bv, C, 0, 0, 0)

__device__ __forceinline__ float sigf(float x) { return 1.0f / (1.0f + __expf(-x)); }
__device__ __forceinline__ float tanh_(float x) {
  float xc = fminf(fmaxf(x, -15.f), 15.f);
  float e = __expf(2.f * xc);
  return (e - 1.f) / (e + 1.f);
}
__device__ __forceinline__ ushort_t f2bf(float f) {
  unsigned u = __float_as_uint(f);
  u = (u + 0x7FFFu + ((u >> 16) & 1u)) >> 16;
  return (ushort_t)u;
}
__device__ __forceinline__ bf16x8 pack8(float4 a, float4 b) {
  bf16x8 v;
  v[0] = (short)f2bf(a.x); v[1] = (short)f2bf(a.y);
  v[2] = (short)f2bf(a.z); v[3] = (short)f2bf(a.w);
  v[4] = (short)f2bf(b.x); v[5] = (short)f2bf(b.y);
  v[6] = (short)f2bf(b.z); v[7] = (short)f2bf(b.w);
  return v;
}
// gate update: a = {pre_i, pre_f, pre_g, pre_o}; returns h, updates c
__device__ __forceinline__ float cellup(const f32x4 a, float& c) {
  float ig = sigf(a[0]), fg = sigf(a[1]), gg = tanh_(a[2]), og = sigf(a[3]);
  c = fg * c + ig * gg;
  return og * tanh_(c);
}

// Precompute Xbf[t][b][d] = bf16(X[b][t][d])
__global__ __launch_bounds__(256) void xbf_k(const float* __restrict__ X,
                                             ushort_t* __restrict__ xbf) {
  const int t = blockIdx.x, tid = threadIdx.x;
  const int b = tid >> 2, dq = (tid & 3) * 32;
  const float* src = X + ((size_t)b * kT + t) * kD + dq;
  ushort_t* dst = xbf + ((size_t)t * kB + b) * kD + dq;
  #pragma unroll
  for (int i = 0; i < 32; i += 8) {
    float4 u0 = *(const float4*)(src + i);
    float4 u1 = *(const float4*)(src + i + 4);
    *(bf16x8*)(dst + i) = pack8(u0, u1);
  }
}

// x-projection MFMAs (K=128 from Xbf[t], direct global reads)
__device__ __forceinline__ void xproj(const ushort_t* xb0, int q, const bf16x8* Ax,
                                      f32x4& a0, f32x4& a1, f32x4& a2, f32x4& a3,
                                      int b0n, int b1n, int b2n, int b3n) {
  #pragma unroll
  for (int ks = 0; ks < 4; ++ks) {
    const int ko = ks * 32 + q * 8;
    bf16x8 x0 = *(const bf16x8*)(xb0 + b0n * 128 + ko);
    bf16x8 x1 = *(const bf16x8*)(xb0 + b1n * 128 + ko);
    bf16x8 x2 = *(const bf16x8*)(xb0 + b2n * 128 + ko);
    bf16x8 x3 = *(const bf16x8*)(xb0 + b3n * 128 + ko);
    MFMA_B16(Ax[ks], x0, a0);
    MFMA_B16(Ax[ks], x1, a1);
    MFMA_B16(Ax[ks], x2, a2);
    MFMA_B16(Ax[ks], x3, a3);
  }
}

// Persistent MFMA LSTM. MODE 0: encoder (grid 64: WGs 0..31 fwd, 32..63 bwd).
// MODE 1: decoder (grid 32; writes y fp32 [t][j][b]).
// WG owns 16 j's; wave w owns j4 = 16*gl + 4w .. +4, all 4 gates, all 64 b.
template<int MODE>
__global__ __launch_bounds__(256, 1) void lstm_k(
    const float* __restrict__ WhhA, const float* __restrict__ WhhB,
    const float* __restrict__ WihA, const float* __restrict__ WihB,
    const float* __restrict__ biaA, const float* __restrict__ biaB,
    const int* __restrict__ lengths, const ushort_t* __restrict__ xbf,
    float* __restrict__ ws) {
  __shared__ ushort_t hlds[32768];   // 64KB, swizzled [b][k] bf16
  __shared__ ushort_t hx[64 * 20];   // h-write transpose bounce
  const int tid = threadIdx.x;
  const int bid = blockIdx.x;
  const bool fwd = (MODE == 1) ? true : (bid < 32);
  const int gl = (MODE == 1) ? bid : (bid & 31);
  const float* Whh = fwd ? WhhA : WhhB;
  const float* Wih = fwd ? WihA : WihB;
  const float* bia = fwd ? biaA : biaB;
  const int dir_off = (MODE == 1) ? 2 : (fwd ? 0 : 1);
  ushort_t* hT = (ushort_t*)(ws + OFF_HT) + dir_off * 65536;
  int* rdy = (int*)(ws + OFF_RDY) + dir_off * 512;
  const int TS = (MODE == 1) ? (kT - 1) : kT;

  const int w = tid >> 6, lane = tid & 63;
  const int q = lane >> 4, r = lane & 15;
  const int JB = gl * 16;
  const int j4 = JB + 4 * w;
  const int gate = r & 3, jj = j4 + (r >> 2);

  // A fragments: Whh rows (16 k-steps) + Wih rows (4 k-steps), bf16 in VGPRs
  bf16x8 Ah[16], Ax[4];
  {
    const float* p = Whh + ((size_t)(gate * kH + jj)) * kH + q * 8;
    #pragma unroll
    for (int ks = 0; ks < 16; ++ks)
      Ah[ks] = pack8(*(const float4*)(p + ks * 32), *(const float4*)(p + ks * 32 + 4));
    const float* px = Wih + ((size_t)(gate * kH + jj)) * kD + q * 8;
    #pragma unroll
    for (int ks = 0; ks < 4; ++ks)
      Ax[ks] = pack8(*(const float4*)(px + ks * 32), *(const float4*)(px + ks * 32 + 4));
  }
  const int jq = j4 + q;
  f32x4 bias_v;
  bias_v[0] = bia[0 * kH + jq];
  bias_v[1] = bia[1 * kH + jq];
  bias_v[2] = bia[2 * kH + jq];
  bias_v[3] = bia[3 * kH + jq];
  const int b0n = r, b1n = 16 + r, b2n = 32 + r, b3n = 48 + r;
  int len0 = 0, len1 = 0, len2 = 0, len3 = 0;
  if (MODE == 0) {
    len0 = lengths[b0n]; len1 = lengths[b1n];
    len2 = lengths[b2n]; len3 = lengths[b3n];
  }
  float c0 = 0.f, c1 = 0.f, c2 = 0.f, c3 = 0.f;
  float hs0 = 0.f, hs1 = 0.f, hs2 = 0.f, hs3 = 0.f;
  f32x4 a0 = bias_v, a1 = bias_v, a2 = bias_v, a3 = bias_v;
  // x-projection for t=0 (enc-bwd reads reversed time)
  {
    const int tx = fwd ? 0 : (kT - 1);
    xproj(xbf + (size_t)tx * 8192, q, Ax, a0, a1, a2, a3, b0n, b1n, b2n, b3n);
  }
  char* lp = (char*)hlds;
  float* yout = ws + OFF_Y;

  for (int t = 0; t < TS; ++t) {
    if (t > 0) {
      if (tid == 0) {
        while (__hip_atomic_load(rdy + t, __ATOMIC_ACQUIRE, __HIP_MEMORY_SCOPE_AGENT) < 32)
          __builtin_amdgcn_s_sleep(1);
      }
      __syncthreads();
    }
    // stage h[t&1] -> LDS, XOR-swizzled
    {
      const ushort_t* hsrc = hT + (t & 1) * 32768;
      #pragma unroll
      for (int i = 0; i < 16; ++i) {
        const int idx = tid + i * 256;        // 16B chunk id
        const int bb = idx >> 6, cc = idx & 63;
        uint4 v = *(const uint4*)(hsrc + bb * 512 + cc * 8);
        *(uint4*)(lp + (((bb << 10) + (cc << 4)) ^ ((bb & 7) << 4))) = v;
      }
    }
    __syncthreads();
    // recurrent MFMAs: 16 k-steps x 4 b-tiles
    #pragma unroll
    for (int ks = 0; ks < 16; ++ks) {
      const int kb = ks * 64 + (q << 4);
      bf16x8 v0 = *(const bf16x8*)(lp + (((b0n << 10) + kb) ^ ((b0n & 7) << 4)));
      bf16x8 v1 = *(const bf16x8*)(lp + (((b1n << 10) + kb) ^ ((b1n & 7) << 4)));
      bf16x8 v2 = *(const bf16x8*)(lp + (((b2n << 10) + kb) ^ ((b2n & 7) << 4)));
      bf16x8 v3 = *(const bf16x8*)(lp + (((b3n << 10) + kb) ^ ((b3n & 7) << 4)));
      MFMA_B16(Ah[ks], v0, a0);
      MFMA_B16(Ah[ks], v1, a1);
      MFMA_B16(Ah[ks], v2, a2);
      MFMA_B16(Ah[ks], v3, a3);
    }
    // pointwise cell update (all 4 gates live in this lane's acc regs)
    const float h0v = cellup(a0, c0);
    const float h1v = cellup(a1, c1);
    const float h2v = cellup(a2, c2);
    const float h3v = cellup(a3, c3);
    if (MODE == 0) {
      const bool m0 = fwd ? (t < len0) : (t >= kT - len0);
      const bool m1 = fwd ? (t < len1) : (t >= kT - len1);
      const bool m2 = fwd ? (t < len2) : (t >= kT - len2);
      const bool m3 = fwd ? (t < len3) : (t >= kT - len3);
      hs0 += m0 ? h0v : 0.f;
      hs1 += m1 ? h1v : 0.f;
      hs2 += m2 ? h2v : 0.f;
      hs3 += m3 ? h3v : 0.f;
    } else {
      yout[((size_t)t * kH + jq) * kB + b0n] = h0v;
      yout[((size_t)t * kH + jq) * kB + b1n] = h1v;
      yout[((size_t)t * kH + jq) * kB + b2n] = h2v;
      yout[((size_t)t * kH + jq) * kB + b3n] = h3v;
    }
    if (t < TS - 1) {
      // h -> bf16, transpose-bounce through LDS, coalesced global write
      const int jl = 4 * w + q;
      hx[b0n * 20 + jl] = f2bf(h0v);
      hx[b1n * 20 + jl] = f2bf(h1v);
      hx[b2n * 20 + jl] = f2bf(h2v);
      hx[b3n * 20 + jl] = f2bf(h3v);
      __syncthreads();
      {
        const int bb = tid >> 2, c4 = (tid & 3) * 4;
        ushort4 v = *(const ushort4*)&hx[bb * 20 + c4];
        *(ushort4*)(hT + ((t + 1) & 1) * 32768 + bb * 512 + JB + c4) = v;
      }
      __syncthreads();
      if (tid == 0) {
        __threadfence();
        __hip_atomic_fetch_add(rdy + (t + 1), 1, __ATOMIC_RELEASE, __HIP_MEMORY_SCOPE_AGENT);
      }
      // reset acc and overlap next step's x-projection with the barrier wait
      a0 = bias_v; a1 = bias_v; a2 = bias_v; a3 = bias_v;
      const int tx = fwd ? (t + 1) : (kT - 1 - (t + 1));
      xproj(xbf + (size_t)tx * 8192, q, Ax, a0, a1, a2, a3, b0n, b1n, b2n, b3n);
    } else if (MODE == 0) {
      float* hfin = ws + (fwd ? OFF_HFF : OFF_HFB);
      float* hsum = ws + (fwd ? OFF_HSF : OFF_HSB);
      hfin[jq * kB + b0n] = h0v; hfin[jq * kB + b1n] = h1v;
      hfin[jq * kB + b2n] = h2v; hfin[jq * kB + b3n] = h3v;
      hsum[jq * kB + b0n] = hs0; hsum[jq * kB + b1n] = hs1;
      hsum[jq * kB + b2n] = hs2; hsum[jq * kB + b3n] = hs3;
    }
  }
}

// latent = [hf, hb, mean_f, mean_b] @ W_lat^T + b_lat ; h_dec = latent @ W_l2h^T + b_l2h
// one WG per batch element; writes bf16 h_dec into decoder hT buffer 0 ([b][j]).
__global__ __launch_bounds__(256) void latent_k(
    const float* __restrict__ W_lat, const float* __restrict__ b_lat,
    const float* __restrict__ W_l2h, const float* __restrict__ b_l2h,
    const int* __restrict__ lengths, float* __restrict__ ws) {
  __shared__ __align__(16) float li[4 * kH];
  __shared__ __align__(16) float ls[kLat];
  const int b = blockIdx.x;
  const int tid = threadIdx.x;
  const float invlen = 1.0f / (float)lengths[b];
  for (int j = tid; j < kH; j += 256) {
    li[j]          = ws[OFF_HFF + (size_t)j * kB + b];
    li[kH + j]     = ws[OFF_HFB + (size_t)j * kB + b];
    li[2 * kH + j] = ws[OFF_HSF + (size_t)j * kB + b] * invlen;
    li[3 * kH + j] = ws[OFF_HSB + (size_t)j * kB + b] * invlen;
  }
  __syncthreads();
  if (tid < kLat) {
    const float* wv = W_lat + (size_t)tid * (4 * kH);
    float a = b_lat[tid];
    for (int k = 0; k < 4 * kH; k += 4) {
      const float4 w4 = *(const float4*)(wv + k);
      a += w4.x * li[k] + w4.y * li[k + 1] + w4.z * li[k + 2] + w4.w * li[k + 3];
    }
    ls[tid] = a;
  }
  __syncthreads();
  ushort_t* hTd = (ushort_t*)(ws + OFF_HT) + 2 * 65536;  // decoder buf 0
  for (int j = tid; j < kH; j += 256) {
    const float* wv = W_l2h + (size_t)j * kLat;
    float a = b_l2h[j];
    #pragma unroll
    for (int k = 0; k < kLat; k += 4) {
      const float4 w4 = *(const float4*)(wv + k);
      a += w4.x * ls[k] + w4.y * ls[k + 1] + w4.z * ls[k + 2] + w4.w * ls[k + 3];
    }
    hTd[b * kH + j] = f2bf(a);
  }
}

// decoded = y @ W_out^T + b_out ; out = alpha*decoded + (1-alpha)*X[:,1:,:]
__global__ __launch_bounds__(256) void out_k(
    const float* __restrict__ X, const float* __restrict__ W_out,
    const float* __restrict__ b_out, const float* __restrict__ alpha_p,
    const float* __restrict__ ws, float* __restrict__ out) {
  __shared__ __align__(16) float ys[128 * 64];
  __shared__ __align__(16) float Wo[128 * 128];
  const int t = blockIdx.x;  // 0..510
  const float* y = ws + OFF_Y + (size_t)t * kH * kB;
  const int tid = threadIdx.x;
  float acc[8][4];
  #pragma unroll
  for (int i = 0; i < 8; ++i)
    #pragma unroll
    for (int jj = 0; jj < 4; ++jj) acc[i][jj] = 0.f;
  const int tg = tid >> 4, tb = tid & 15;
  const int d0 = tg * 8, b0 = tb * 4;
  for (int ch = 0; ch < 4; ++ch) {
    __syncthreads();
    {
      const float4* s4 = (const float4*)(y + ch * 128 * 64);
      float4* d4 = (float4*)ys;
      #pragma unroll
      for (int i = 0; i < 8; ++i) d4[tid + i * 256] = s4[tid + i * 256];
    }
    {
      const int d = tid & 127, k0 = (tid >> 7) * 64;
      const float* src = W_out + (size_t)d * kH + ch * 128 + k0;
      #pragma unroll
      for (int i = 0; i < 64; i += 4) {
        float4 v = *(const float4*)(src + i);
        Wo[(k0 + i + 0) * 128 + d] = v.x;
        Wo[(k0 + i + 1) * 128 + d] = v.y;
        Wo[(k0 + i + 2) * 128 + d] = v.z;
        Wo[(k0 + i + 3) * 128 + d] = v.w;
      }
    }
    __syncthreads();
    #pragma unroll 2
    for (int k = 0; k < 128; ++k) {
      const float4 yv = *(const float4*)&ys[k * 64 + b0];
      const float4 w0 = *(const float4*)&Wo[k * 128 + d0];
      const float4 w1 = *(const float4*)&Wo[k * 128 + d0 + 4];
      const float wv[8] = {w0.x, w0.y, w0.z, w0.w, w1.x, w1.y, w1.z, w1.w};
      const float ya[4] = {yv.x, yv.y, yv.z, yv.w};
      #pragma unroll
      for (int di = 0; di < 8; ++di)
        #pragma unroll
        for (int bi = 0; bi < 4; ++bi)
          acc[di][bi] += wv[di] * ya[bi];
    }
  }
  const float alpha = sigf(alpha_p[0]);
  const float beta = 1.0f - alpha;
  #pragma unroll
  for (int bi = 0; bi < 4; ++bi) {
    const int b = b0 + bi;
    const float* xrow = X + ((size_t)b * kT + t + 1) * kD + d0;
    float* orow = out + ((size_t)b * (kT - 1) + t) * kD + d0;
    #pragma unroll
    for (int di = 0; di < 8; di += 4) {
      const float4 xv = *(const float4*)(xrow + di);
      float4 o;
      o.x = alpha * (acc[di + 0][bi] + b_out[d0 + di + 0]) + beta * xv.x;
      o.y = alpha * (acc[di + 1][bi] + b_out[d0 + di + 1]) + beta * xv.y;
      o.z = alpha * (acc[di + 2][bi] + b_out[d0 + di + 2]) + beta * xv.z;
      o.w = alpha * (acc[di + 3][bi] + b_out[d0 + di + 3]) + beta * xv.w;
      *(float4*)(orow + di) = o;
    }
  }
}

// Diagnostic fallback if workspace is too small: out = (1-alpha)*X[:,1:,:]
__global__ __launch_bounds__(256) void fallback_k(
    const float* __restrict__ X, const float* __restrict__ alpha_p,
    float* __restrict__ out, int n) {
  const int o = blockIdx.x * 256 + threadIdx.x;
  if (o >= n) return;
  const float alpha = sigf(alpha_p[0]);
  const int b = o / ((kT - 1) * kD);
  const int rr = o % ((kT - 1) * kD);
  const int t = rr / kD, d = rr % kD;
  out[o] = (1.0f - alpha) * X[((size_t)b * kT + t + 1) * kD + d];
}

extern "C" void kernel_launch(void* const* d_in, const int* in_sizes, int n_in,
                              void* d_out, int out_size, void* d_ws, size_t ws_size,
                              hipStream_t stream) {
  const float* X      = (const float*)d_in[0];
  const int*   lens   = (const int*)  d_in[1];
  const float* W_ih_f = (const float*)d_in[2];
  const float* W_hh_f = (const float*)d_in[3];
  const float* b_f    = (const float*)d_in[4];
  const float* W_ih_b = (const float*)d_in[5];
  const float* W_hh_b = (const float*)d_in[6];
  const float* b_b    = (const float*)d_in[7];
  const float* W_ih_d = (const float*)d_in[8];
  const float* W_hh_d = (const float*)d_in[9];
  const float* b_d    = (const float*)d_in[10];
  const float* W_lat  = (const float*)d_in[11];
  const float* b_lat  = (const float*)d_in[12];
  const float* W_l2h  = (const float*)d_in[13];
  const float* b_l2h  = (const float*)d_in[14];
  const float* W_out  = (const float*)d_in[15];
  const float* b_out  = (const float*)d_in[16];
  const float* alpha  = (const float*)d_in[17];
  float* ws  = (float*)d_ws;
  float* out = (float*)d_out;

  if (ws_size < NEED_BYTES) {
    fallback_k<<<(out_size + 255) / 256, 256, 0, stream>>>(X, alpha, out, out_size);
    return;
  }

  // zero hT buffers (bf16 zeros) + ready counters (contiguous region)
  hipMemsetAsync((void*)(ws + OFF_HT), 0, (HT_F + 2048) * sizeof(float), stream);

  ushort_t* xbf = (ushort_t*)(ws + OFF_XBF);
  // bf16 input cast, [t][b][d]
  xbf_k<<<kT, 256, 0, stream>>>(X, xbf);
  // encoder: 32 WGs fwd + 32 WGs bwd, persistent MFMA LSTM
  lstm_k<0><<<64, 256, 0, stream>>>(W_hh_f, W_hh_b, W_ih_f, W_ih_b, b_f, b_b,
                                    lens, xbf, ws);
  // latent + decoder initial hidden (bf16)
  latent_k<<<64, 256, 0, stream>>>(W_lat, b_lat, W_l2h, b_l2h, lens, ws);
  // decoder: 32 WGs persistent MFMA LSTM, y fp32 into OFF_Y
  lstm_k<1><<<32, 256, 0, stream>>>(W_hh_d, nullptr, W_ih_d, nullptr, b_d, nullptr,
                                    lens, xbf, ws);
  // output projection + skip connection
  out_k<<<kT - 1, 256, 0, stream>>>(X, W_out, b_out, alpha, ws, out);
}

// Round 4
// 5602.721 us; speedup vs baseline: 6.2202x; 1.8753x over previous
//
#include <hip/hip_runtime.h>
#include <cstdint>
#include <cstddef>

typedef __attribute__((ext_vector_type(8))) short bf16x8;
typedef __attribute__((ext_vector_type(4))) float f32x4;
typedef __attribute__((ext_vector_type(4))) unsigned u32x4;
typedef __attribute__((ext_vector_type(2))) unsigned u32x2;
typedef unsigned short ushort_t;

// Problem constants
constexpr int kB = 64;
constexpr int kT = 512;
constexpr int kD = 128;
constexpr int kH = 512;
constexpr int kLat = 128;

// Workspace layout (float element offsets), total ~76.5 MB
constexpr size_t OFF_Y   = 0;                        // fp32 y [511][512][64]
constexpr size_t Y_EL    = (size_t)(kT - 1) * kH * kB;      // 16,744,448
constexpr size_t OFF_XBF = OFF_Y + Y_EL;             // bf16 Xbf [512][64][128] (as ushort)
constexpr size_t XBF_F   = (size_t)kT * kB * kD / 2; // 2,097,152 floats
constexpr size_t OFF_HT  = OFF_XBF + XBF_F;          // bf16 hT: 3 dirs x 2 bufs x 64x512 us
constexpr size_t HT_F    = 3 * 2 * 32768 / 2;        // 98,304 floats
constexpr size_t OFF_RDY = OFF_HT + HT_F;            // flags: 3 dirs x 512 steps x 32 wgs
constexpr size_t RDY_I   = 3 * 512 * 32;             // 49,152 ints
constexpr size_t OFF_HFF = OFF_RDY + RDY_I;          // fp32 [j][b]
constexpr size_t OFF_HFB = OFF_HFF + 32768;
constexpr size_t OFF_HSF = OFF_HFB + 32768;
constexpr size_t OFF_HSB = OFF_HSF + 32768;
constexpr size_t NEED_BYTES = (OFF_HSB + 32768) * 4; // 76,480,512

#define MFMA_B16(A, Bv, C) C = __builtin_amdgcn_mfma_f32_16x16x32_bf16(A, Bv, C, 0, 0, 0)

__device__ __forceinline__ float sigf(float x) { return 1.0f / (1.0f + __expf(-x)); }
__device__ __forceinline__ float tanh_(float x) {
  float xc = fminf(fmaxf(x, -15.f), 15.f);
  float e = __expf(2.f * xc);
  return (e - 1.f) / (e + 1.f);
}
__device__ __forceinline__ ushort_t f2bf(float f) {
  unsigned u = __float_as_uint(f);
  u = (u + 0x7FFFu + ((u >> 16) & 1u)) >> 16;
  return (ushort_t)u;
}
__device__ __forceinline__ bf16x8 pack8(float4 a, float4 b) {
  bf16x8 v;
  v[0] = (short)f2bf(a.x); v[1] = (short)f2bf(a.y);
  v[2] = (short)f2bf(a.z); v[3] = (short)f2bf(a.w);
  v[4] = (short)f2bf(b.x); v[5] = (short)f2bf(b.y);
  v[6] = (short)f2bf(b.z); v[7] = (short)f2bf(b.w);
  return v;
}
// gate update: a = {pre_i, pre_f, pre_g, pre_o}; returns h, updates c
__device__ __forceinline__ float cellup(const f32x4 a, float& c) {
  float ig = sigf(a[0]), fg = sigf(a[1]), gg = tanh_(a[2]), og = sigf(a[3]);
  c = fg * c + ig * gg;
  return og * tanh_(c);
}

// LLC-coherent (bypass L1+L2) accesses — per-access coherence, NO cache-wide ops.
__device__ __forceinline__ u32x4 llc_load_b128(const void* p) {
  u32x4 v;
  asm volatile("global_load_dwordx4 %0, %1, off sc0 sc1"
               : "=v"(v) : "v"(p) : "memory");
  return v;
}
__device__ __forceinline__ void llc_store_b64(void* p, u32x2 v) {
  asm volatile("global_store_dwordx2 %0, %1, off sc0 sc1"
               :: "v"(p), "v"(v) : "memory");
}
__device__ __forceinline__ void llc_store_b32(void* p, unsigned v) {
  asm volatile("global_store_dword %0, %1, off sc0 sc1"
               :: "v"(p), "v"(v) : "memory");
}
__device__ __forceinline__ void wait_vm0() {
  asm volatile("s_waitcnt vmcnt(0)" ::: "memory");
  __builtin_amdgcn_sched_barrier(0);
}

// Precompute Xbf[t][b][d] = bf16(X[b][t][d])
__global__ __launch_bounds__(256) void xbf_k(const float* __restrict__ X,
                                             ushort_t* __restrict__ xbf) {
  const int t = blockIdx.x, tid = threadIdx.x;
  const int b = tid >> 2, dq = (tid & 3) * 32;
  const float* src = X + ((size_t)b * kT + t) * kD + dq;
  ushort_t* dst = xbf + ((size_t)t * kB + b) * kD + dq;
  #pragma unroll
  for (int i = 0; i < 32; i += 8) {
    float4 u0 = *(const float4*)(src + i);
    float4 u1 = *(const float4*)(src + i + 4);
    *(bf16x8*)(dst + i) = pack8(u0, u1);
  }
}

// x-projection MFMAs (K=128 from Xbf[t], direct global reads, L2-cached)
__device__ __forceinline__ void xproj(const ushort_t* xb0, int q, const bf16x8* Ax,
                                      f32x4& a0, f32x4& a1, f32x4& a2, f32x4& a3,
                                      int b0n, int b1n, int b2n, int b3n) {
  #pragma unroll
  for (int ks = 0; ks < 4; ++ks) {
    const int ko = ks * 32 + q * 8;
    bf16x8 x0 = *(const bf16x8*)(xb0 + b0n * 128 + ko);
    bf16x8 x1 = *(const bf16x8*)(xb0 + b1n * 128 + ko);
    bf16x8 x2 = *(const bf16x8*)(xb0 + b2n * 128 + ko);
    bf16x8 x3 = *(const bf16x8*)(xb0 + b3n * 128 + ko);
    MFMA_B16(Ax[ks], x0, a0);
    MFMA_B16(Ax[ks], x1, a1);
    MFMA_B16(Ax[ks], x2, a2);
    MFMA_B16(Ax[ks], x3, a3);
  }
}

// Persistent MFMA LSTM. MODE 0: encoder (grid 64: WGs 0..31 fwd, 32..63 bwd).
// MODE 1: decoder (grid 32; writes y fp32 [t][j][b]).
// WG owns 16 j's; wave w owns j4 = 16*gl + 4w .. +4, all 4 gates, all 64 b.
template<int MODE>
__global__ __launch_bounds__(256, 1) void lstm_k(
    const float* __restrict__ WhhA, const float* __restrict__ WhhB,
    const float* __restrict__ WihA, const float* __restrict__ WihB,
    const float* __restrict__ biaA, const float* __restrict__ biaB,
    const int* __restrict__ lengths, const ushort_t* __restrict__ xbf,
    float* __restrict__ ws) {
  __shared__ ushort_t hlds[32768];   // 64KB, swizzled [b][k] bf16
  __shared__ ushort_t hx[64 * 20];   // h-write transpose bounce
  const int tid = threadIdx.x;
  const int bid = blockIdx.x;
  const bool fwd = (MODE == 1) ? true : (bid < 32);
  const int gl = (MODE == 1) ? bid : (bid & 31);
  const float* Whh = fwd ? WhhA : WhhB;
  const float* Wih = fwd ? WihA : WihB;
  const float* bia = fwd ? biaA : biaB;
  const int dir_off = (MODE == 1) ? 2 : (fwd ? 0 : 1);
  ushort_t* hT = (ushort_t*)(ws + OFF_HT) + dir_off * 65536;
  unsigned* rdyf = (unsigned*)(ws + OFF_RDY) + (size_t)dir_off * 512 * 32;
  const int TS = (MODE == 1) ? (kT - 1) : kT;

  const int w = tid >> 6, lane = tid & 63;
  const int q = lane >> 4, r = lane & 15;
  const int JB = gl * 16;
  const int j4 = JB + 4 * w;
  const int gate = r & 3, jj = j4 + (r >> 2);

  // A fragments: Whh rows (16 k-steps) + Wih rows (4 k-steps), bf16 in VGPRs
  bf16x8 Ah[16], Ax[4];
  {
    const float* p = Whh + ((size_t)(gate * kH + jj)) * kH + q * 8;
    #pragma unroll
    for (int ks = 0; ks < 16; ++ks)
      Ah[ks] = pack8(*(const float4*)(p + ks * 32), *(const float4*)(p + ks * 32 + 4));
    const float* px = Wih + ((size_t)(gate * kH + jj)) * kD + q * 8;
    #pragma unroll
    for (int ks = 0; ks < 4; ++ks)
      Ax[ks] = pack8(*(const float4*)(px + ks * 32), *(const float4*)(px + ks * 32 + 4));
  }
  const int jq = j4 + q;
  f32x4 bias_v;
  bias_v[0] = bia[0 * kH + jq];
  bias_v[1] = bia[1 * kH + jq];
  bias_v[2] = bia[2 * kH + jq];
  bias_v[3] = bia[3 * kH + jq];
  const int b0n = r, b1n = 16 + r, b2n = 32 + r, b3n = 48 + r;
  int len0 = 0, len1 = 0, len2 = 0, len3 = 0;
  if (MODE == 0) {
    len0 = lengths[b0n]; len1 = lengths[b1n];
    len2 = lengths[b2n]; len3 = lengths[b3n];
  }
  float c0 = 0.f, c1 = 0.f, c2 = 0.f, c3 = 0.f;
  float hs0 = 0.f, hs1 = 0.f, hs2 = 0.f, hs3 = 0.f;
  f32x4 a0 = bias_v, a1 = bias_v, a2 = bias_v, a3 = bias_v;
  // x-projection for t=0 (enc-bwd reads reversed time)
  {
    const int tx = fwd ? 0 : (kT - 1);
    xproj(xbf + (size_t)tx * 8192, q, Ax, a0, a1, a2, a3, b0n, b1n, b2n, b3n);
  }
  char* lp = (char*)hlds;
  float* yout = ws + OFF_Y;

  for (int t = 0; t < TS; ++t) {
    // wait until all 32 producer WGs have published h[t] (skip at t=0)
    if (t > 0) {
      if (w == 0) {
        const unsigned* fp = rdyf + (size_t)t * 32 + (lane & 31);
        for (;;) {
          unsigned v = __hip_atomic_load(fp, __ATOMIC_RELAXED, __HIP_MEMORY_SCOPE_AGENT);
          if (__ballot(v != 0u) == ~0ull) break;
          __builtin_amdgcn_s_sleep(1);
        }
        __builtin_amdgcn_sched_barrier(0);
      }
      __syncthreads();
    }
    // stage h[t&1] -> LDS, XOR-swizzled (LLC-coherent bulk loads)
    {
      const char* hsrc = (const char*)(hT + (t & 1) * 32768);
      u32x4 reg[16];
      #pragma unroll
      for (int i = 0; i < 16; ++i) {
        const int idx = tid + i * 256;        // 16B chunk id
        reg[i] = llc_load_b128(hsrc + (size_t)idx * 16);
      }
      wait_vm0();
      #pragma unroll
      for (int i = 0; i < 16; ++i) {
        const int idx = tid + i * 256;
        const int bb = idx >> 6, cc = idx & 63;
        *(u32x4*)(lp + (((bb << 10) + (cc << 4)) ^ ((bb & 7) << 4))) = reg[i];
      }
    }
    __syncthreads();
    // recurrent MFMAs: 16 k-steps x 4 b-tiles
    #pragma unroll
    for (int ks = 0; ks < 16; ++ks) {
      const int kb = ks * 64 + (q << 4);
      bf16x8 v0 = *(const bf16x8*)(lp + (((b0n << 10) + kb) ^ ((b0n & 7) << 4)));
      bf16x8 v1 = *(const bf16x8*)(lp + (((b1n << 10) + kb) ^ ((b1n & 7) << 4)));
      bf16x8 v2 = *(const bf16x8*)(lp + (((b2n << 10) + kb) ^ ((b2n & 7) << 4)));
      bf16x8 v3 = *(const bf16x8*)(lp + (((b3n << 10) + kb) ^ ((b3n & 7) << 4)));
      MFMA_B16(Ah[ks], v0, a0);
      MFMA_B16(Ah[ks], v1, a1);
      MFMA_B16(Ah[ks], v2, a2);
      MFMA_B16(Ah[ks], v3, a3);
    }
    // pointwise cell update (all 4 gates live in this lane's acc regs)
    const float h0v = cellup(a0, c0);
    const float h1v = cellup(a1, c1);
    const float h2v = cellup(a2, c2);
    const float h3v = cellup(a3, c3);
    if (MODE == 0) {
      const bool m0 = fwd ? (t < len0) : (t >= kT - len0);
      const bool m1 = fwd ? (t < len1) : (t >= kT - len1);
      const bool m2 = fwd ? (t < len2) : (t >= kT - len2);
      const bool m3 = fwd ? (t < len3) : (t >= kT - len3);
      hs0 += m0 ? h0v : 0.f;
      hs1 += m1 ? h1v : 0.f;
      hs2 += m2 ? h2v : 0.f;
      hs3 += m3 ? h3v : 0.f;
    } else {
      yout[((size_t)t * kH + jq) * kB + b0n] = h0v;
      yout[((size_t)t * kH + jq) * kB + b1n] = h1v;
      yout[((size_t)t * kH + jq) * kB + b2n] = h2v;
      yout[((size_t)t * kH + jq) * kB + b3n] = h3v;
    }
    if (t < TS - 1) {
      // h -> bf16, transpose-bounce through LDS, coalesced LLC-coherent write
      const int jl = 4 * w + q;
      hx[b0n * 20 + jl] = f2bf(h0v);
      hx[b1n * 20 + jl] = f2bf(h1v);
      hx[b2n * 20 + jl] = f2bf(h2v);
      hx[b3n * 20 + jl] = f2bf(h3v);
      __syncthreads();
      {
        const int bb = tid >> 2, c4 = (tid & 3) * 4;
        u32x2 v = *(const u32x2*)&hx[bb * 20 + c4];
        llc_store_b64(hT + ((t + 1) & 1) * 32768 + bb * 512 + JB + c4, v);
      }
      // barrier drains vmcnt(0) for every thread -> all h stores acked at LLC
      __syncthreads();
      if (tid == 0) llc_store_b32(rdyf + (size_t)(t + 1) * 32 + gl, 1u);
      // reset acc and overlap next step's x-projection with others' polling
      a0 = bias_v; a1 = bias_v; a2 = bias_v; a3 = bias_v;
      const int tx = fwd ? (t + 1) : (kT - 1 - (t + 1));
      xproj(xbf + (size_t)tx * 8192, q, Ax, a0, a1, a2, a3, b0n, b1n, b2n, b3n);
    } else if (MODE == 0) {
      float* hfin = ws + (fwd ? OFF_HFF : OFF_HFB);
      float* hsum = ws + (fwd ? OFF_HSF : OFF_HSB);
      hfin[jq * kB + b0n] = h0v; hfin[jq * kB + b1n] = h1v;
      hfin[jq * kB + b2n] = h2v; hfin[jq * kB + b3n] = h3v;
      hsum[jq * kB + b0n] = hs0; hsum[jq * kB + b1n] = hs1;
      hsum[jq * kB + b2n] = hs2; hsum[jq * kB + b3n] = hs3;
    }
  }
}

// latent = [hf, hb, mean_f, mean_b] @ W_lat^T + b_lat ; h_dec = latent @ W_l2h^T + b_l2h
// one WG per batch element; writes bf16 h_dec into decoder hT buffer 0 ([b][j]).
__global__ __launch_bounds__(256) void latent_k(
    const float* __restrict__ W_lat, const float* __restrict__ b_lat,
    const float* __restrict__ W_l2h, const float* __restrict__ b_l2h,
    const int* __restrict__ lengths, float* __restrict__ ws) {
  __shared__ __align__(16) float li[4 * kH];
  __shared__ __align__(16) float ls[kLat];
  const int b = blockIdx.x;
  const int tid = threadIdx.x;
  const float invlen = 1.0f / (float)lengths[b];
  for (int j = tid; j < kH; j += 256) {
    li[j]          = ws[OFF_HFF + (size_t)j * kB + b];
    li[kH + j]     = ws[OFF_HFB + (size_t)j * kB + b];
    li[2 * kH + j] = ws[OFF_HSF + (size_t)j * kB + b] * invlen;
    li[3 * kH + j] = ws[OFF_HSB + (size_t)j * kB + b] * invlen;
  }
  __syncthreads();
  if (tid < kLat) {
    const float* wv = W_lat + (size_t)tid * (4 * kH);
    float a = b_lat[tid];
    for (int k = 0; k < 4 * kH; k += 4) {
      const float4 w4 = *(const float4*)(wv + k);
      a += w4.x * li[k] + w4.y * li[k + 1] + w4.z * li[k + 2] + w4.w * li[k + 3];
    }
    ls[tid] = a;
  }
  __syncthreads();
  ushort_t* hTd = (ushort_t*)(ws + OFF_HT) + 2 * 65536;  // decoder buf 0
  for (int j = tid; j < kH; j += 256) {
    const float* wv = W_l2h + (size_t)j * kLat;
    float a = b_l2h[j];
    #pragma unroll
    for (int k = 0; k < kLat; k += 4) {
      const float4 w4 = *(const float4*)(wv + k);
      a += w4.x * ls[k] + w4.y * ls[k + 1] + w4.z * ls[k + 2] + w4.w * ls[k + 3];
    }
    hTd[b * kH + j] = f2bf(a);
  }
}

// decoded = y @ W_out^T + b_out ; out = alpha*decoded + (1-alpha)*X[:,1:,:]
__global__ __launch_bounds__(256) void out_k(
    const float* __restrict__ X, const float* __restrict__ W_out,
    const float* __restrict__ b_out, const float* __restrict__ alpha_p,
    const float* __restrict__ ws, float* __restrict__ out) {
  __shared__ __align__(16) float ys[128 * 64];
  __shared__ __align__(16) float Wo[128 * 128];
  const int t = blockIdx.x;  // 0..510
  const float* y = ws + OFF_Y + (size_t)t * kH * kB;
  const int tid = threadIdx.x;
  float acc[8][4];
  #pragma unroll
  for (int i = 0; i < 8; ++i)
    #pragma unroll
    for (int jj = 0; jj < 4; ++jj) acc[i][jj] = 0.f;
  const int tg = tid >> 4, tb = tid & 15;
  const int d0 = tg * 8, b0 = tb * 4;
  for (int ch = 0; ch < 4; ++ch) {
    __syncthreads();
    {
      const float4* s4 = (const float4*)(y + ch * 128 * 64);
      float4* d4 = (float4*)ys;
      #pragma unroll
      for (int i = 0; i < 8; ++i) d4[tid + i * 256] = s4[tid + i * 256];
    }
    {
      const int d = tid & 127, k0 = (tid >> 7) * 64;
      const float* src = W_out + (size_t)d * kH + ch * 128 + k0;
      #pragma unroll
      for (int i = 0; i < 64; i += 4) {
        float4 v = *(const float4*)(src + i);
        Wo[(k0 + i + 0) * 128 + d] = v.x;
        Wo[(k0 + i + 1) * 128 + d] = v.y;
        Wo[(k0 + i + 2) * 128 + d] = v.z;
        Wo[(k0 + i + 3) * 128 + d] = v.w;
      }
    }
    __syncthreads();
    #pragma unroll 2
    for (int k = 0; k < 128; ++k) {
      const float4 yv = *(const float4*)&ys[k * 64 + b0];
      const float4 w0 = *(const float4*)&Wo[k * 128 + d0];
      const float4 w1 = *(const float4*)&Wo[k * 128 + d0 + 4];
      const float wv[8] = {w0.x, w0.y, w0.z, w0.w, w1.x, w1.y, w1.z, w1.w};
      const float ya[4] = {yv.x, yv.y, yv.z, yv.w};
      #pragma unroll
      for (int di = 0; di < 8; ++di)
        #pragma unroll
        for (int bi = 0; bi < 4; ++bi)
          acc[di][bi] += wv[di] * ya[bi];
    }
  }
  const float alpha = sigf(alpha_p[0]);
  const float beta = 1.0f - alpha;
  #pragma unroll
  for (int bi = 0; bi < 4; ++bi) {
    const int b = b0 + bi;
    const float* xrow = X + ((size_t)b * kT + t + 1) * kD + d0;
    float* orow = out + ((size_t)b * (kT - 1) + t) * kD + d0;
    #pragma unroll
    for (int di = 0; di < 8; di += 4) {
      const float4 xv = *(const float4*)(xrow + di);
      float4 o;
      o.x = alpha * (acc[di + 0][bi] + b_out[d0 + di + 0]) + beta * xv.x;
      o.y = alpha * (acc[di + 1][bi] + b_out[d0 + di + 1]) + beta * xv.y;
      o.z = alpha * (acc[di + 2][bi] + b_out[d0 + di + 2]) + beta * xv.z;
      o.w = alpha * (acc[di + 3][bi] + b_out[d0 + di + 3]) + beta * xv.w;
      *(float4*)(orow + di) = o;
    }
  }
}

// Diagnostic fallback if workspace is too small: out = (1-alpha)*X[:,1:,:]
__global__ __launch_bounds__(256) void fallback_k(
    const float* __restrict__ X, const float* __restrict__ alpha_p,
    float* __restrict__ out, int n) {
  const int o = blockIdx.x * 256 + threadIdx.x;
  if (o >= n) return;
  const float alpha = sigf(alpha_p[0]);
  const int b = o / ((kT - 1) * kD);
  const int rr = o % ((kT - 1) * kD);
  const int t = rr / kD, d = rr % kD;
  out[o] = (1.0f - alpha) * X[((size_t)b * kT + t + 1) * kD + d];
}

extern "C" void kernel_launch(void* const* d_in, const int* in_sizes, int n_in,
                              void* d_out, int out_size, void* d_ws, size_t ws_size,
                              hipStream_t stream) {
  const float* X      = (const float*)d_in[0];
  const int*   lens   = (const int*)  d_in[1];
  const float* W_ih_f = (const float*)d_in[2];
  const float* W_hh_f = (const float*)d_in[3];
  const float* b_f    = (const float*)d_in[4];
  const float* W_ih_b = (const float*)d_in[5];
  const float* W_hh_b = (const float*)d_in[6];
  const float* b_b    = (const float*)d_in[7];
  const float* W_ih_d = (const float*)d_in[8];
  const float* W_hh_d = (const float*)d_in[9];
  const float* b_d    = (const float*)d_in[10];
  const float* W_lat  = (const float*)d_in[11];
  const float* b_lat  = (const float*)d_in[12];
  const float* W_l2h  = (const float*)d_in[13];
  const float* b_l2h  = (const float*)d_in[14];
  const float* W_out  = (const float*)d_in[15];
  const float* b_out  = (const float*)d_in[16];
  const float* alpha  = (const float*)d_in[17];
  float* ws  = (float*)d_ws;
  float* out = (float*)d_out;

  if (ws_size < NEED_BYTES) {
    fallback_k<<<(out_size + 255) / 256, 256, 0, stream>>>(X, alpha, out, out_size);
    return;
  }

  // zero hT buffers (bf16 zeros) + ready flags (contiguous region)
  hipMemsetAsync((void*)(ws + OFF_HT), 0, (HT_F + RDY_I) * sizeof(float), stream);

  ushort_t* xbf = (ushort_t*)(ws + OFF_XBF);
  // bf16 input cast, [t][b][d]
  xbf_k<<<kT, 256, 0, stream>>>(X, xbf);
  // encoder: 32 WGs fwd + 32 WGs bwd, persistent MFMA LSTM
  lstm_k<0><<<64, 256, 0, stream>>>(W_hh_f, W_hh_b, W_ih_f, W_ih_b, b_f, b_b,
                                    lens, xbf, ws);
  // latent + decoder initial hidden (bf16)
  latent_k<<<64, 256, 0, stream>>>(W_lat, b_lat, W_l2h, b_l2h, lens, ws);
  // decoder: 32 WGs persistent MFMA LSTM, y fp32 into OFF_Y
  lstm_k<1><<<32, 256, 0, stream>>>(W_hh_d, nullptr, W_ih_d, nullptr, b_d, nullptr,
                                    lens, xbf, ws);
  // output projection + skip connection
  out_k<<<kT - 1, 256, 0, stream>>>(X, W_out, b_out, alpha, ws, out);
}